// Round 18
// baseline (66.897 us; speedup 1.0000x reference)
//
#include <hip/hip_runtime.h>
#include <hip/hip_bf16.h>
#include <math.h>

#define CIN 64
#define E   128
#define H3  384
#define FF  256
#define NH  8
#define HD  16
#define NBATCH 4

typedef __attribute__((ext_vector_type(8))) short short8;
typedef __attribute__((ext_vector_type(16))) float f32x16;
typedef __attribute__((ext_vector_type(4))) uint uint4v;

static __device__ __forceinline__ ushort f2bf(float f) {
    uint u = __float_as_uint(f);
    return (ushort)((u + 0x7fffu + ((u >> 16) & 1u)) >> 16);
}
// packed RNE f32x2 -> bf16x2
static __device__ __forceinline__ uint f2bf2(float lo, float hi) {
    uint r;
    asm("v_cvt_pk_bf16_f32 %0, %1, %2" : "=v"(r) : "v"(lo), "v"(hi));
    return r;
}
// row swap between two VGPRs
static __device__ __forceinline__ void plswap(uint& a, uint& b) {
    auto r = __builtin_amdgcn_permlane32_swap(a, b, false, false);
    a = r[0]; b = r[1];
}
// 4 uints -> short8 fragment (SROA-proof)
static __device__ __forceinline__ short8 mk8(uint a, uint b, uint c, uint d) {
    uint4v v; v[0] = a; v[1] = b; v[2] = c; v[3] = d;
    return __builtin_bit_cast(short8, v);
}

// ---------------- weights -> bf16 MFMA B-fragment layout (+ batch bounds, m==5) ----------------
__global__ __launch_bounds__(256) void k_wprep(const float* w0, const float* w1, const float* w2,
                                               const float* w3, const float* w4,
                                               ushort* f0, ushort* f1, ushort* f2,
                                               ushort* f3, ushort* f4,
                                               const int* __restrict__ coords, int n,
                                               int* __restrict__ starts) {
    const int m = blockIdx.y;
    const int t = blockIdx.x * 256 + threadIdx.x;
    if (m == 5) {
        if (t >= n) return;
        int cur = coords[t * 4];
        int prev = (t == 0) ? -1 : coords[(t - 1) * 4];
        for (int bb = prev + 1; bb <= cur; ++bb) starts[bb] = t;
        if (t == n - 1)
            for (int bb = cur + 1; bb <= NBATCH; ++bb) starts[bb] = n;
        return;
    }
    const int Ks[5] = {CIN, E, E, E, FF};
    const int Ms[5] = {E, H3, E, FF, E};
    const float* src = m == 0 ? w0 : m == 1 ? w1 : m == 2 ? w2 : m == 3 ? w3 : w4;
    ushort* dst = m == 0 ? f0 : m == 1 ? f1 : m == 2 ? f2 : m == 3 ? f3 : f4;
    const int K = Ks[m], M = Ms[m];
    const int CT = M / 32;
    const int total = (K / 16) * CT * 64;
    if (t >= total) return;
    const int lane = t & 63;
    const int ct = (t >> 6) % CT;
    const int kt = (t >> 6) / CT;
    const int col = ct * 32 + (lane & 31);
    const int k0 = kt * 16 + 8 * (lane >> 5);
    const float* sp = src + (size_t)k0 * M + col;
    uint a = f2bf2(sp[0], sp[(size_t)M]);
    uint b = f2bf2(sp[2 * (size_t)M], sp[3 * (size_t)M]);
    uint c = f2bf2(sp[4 * (size_t)M], sp[5 * (size_t)M]);
    uint d = f2bf2(sp[6 * (size_t)M], sp[7 * (size_t)M]);
    *(short8*)(dst + (size_t)t * 8) = mk8(a, b, c, d);
}

// ---------------- fused: x = feat@pre_w+pre_b ; qkv = x@in_w+in_b ----------------
// vt2 layout: [h][tile64][slice 0..3][16 dims][16 keys]  (512B dense slices)
__global__ __launch_bounds__(256) void k_preqkv(const float* __restrict__ feat, const ushort* __restrict__ wf0,
        const float* __restrict__ pre_b, const ushort* __restrict__ wf1, const float* __restrict__ in_b,
        float* __restrict__ x, ushort* __restrict__ qh, ushort* __restrict__ kh, ushort* __restrict__ vt2,
        int n, int npk) {
    __shared__ ushort sxb[32][136];
    __shared__ ushort lv[4][32][34];
    const int rt = blockIdx.x;
    const int NT = n >> 6;
    const int tid = threadIdx.x, w = tid >> 6, lane = tid & 63;
    const int l31 = lane & 31, hi = lane >> 5;
    const int row = rt * 32 + l31;
    const int gt = rt >> 1, halfT = rt & 1;   // 64-key tile, which 32-key half
    const float SC = 0.25f * 1.4426950408889634f;
    {
        f32x16 acc;
#pragma unroll
        for (int i = 0; i < 16; ++i) acc[i] = 0.f;
#pragma unroll
        for (int kt = 0; kt < 4; ++kt) {
            const float* ap = feat + (size_t)row * CIN + kt * 16 + 8 * hi;
            const float4 a0 = *(const float4*)ap;
            const float4 a1 = *(const float4*)(ap + 4);
            const short8 af = mk8(f2bf2(a0.x, a0.y), f2bf2(a0.z, a0.w),
                                  f2bf2(a1.x, a1.y), f2bf2(a1.z, a1.w));
            const short8 bf = *(const short8*)(wf0 + ((size_t)(kt * 4 + w) * 64 + lane) * 8);
            acc = __builtin_amdgcn_mfma_f32_32x32x16_bf16(af, bf, acc, 0, 0, 0);
        }
        const int col = w * 32 + l31;
        const float bj = pre_b[col];
#pragma unroll
        for (int r = 0; r < 16; ++r) {
            const int rowl = (r & 3) + 8 * (r >> 2) + 4 * hi;
            const float v = acc[r] + bj;
            x[(size_t)(rt * 32 + rowl) * E + col] = v;
            sxb[rowl][col] = f2bf(v);
        }
    }
    __syncthreads();
#pragma unroll
    for (int c = 0; c < 3; ++c) {
        const int ct = w + 4 * c;
        f32x16 acc;
#pragma unroll
        for (int i = 0; i < 16; ++i) acc[i] = 0.f;
#pragma unroll
        for (int kt = 0; kt < 8; ++kt) {
            const short8 af = *(const short8*)(&sxb[l31][kt * 16 + 8 * hi]);
            const short8 bf = *(const short8*)(wf1 + ((size_t)(kt * 12 + ct) * 64 + lane) * 8);
            acc = __builtin_amdgcn_mfma_f32_32x32x16_bf16(af, bf, acc, 0, 0, 0);
        }
        const int colg = ct * 32 + l31;
        const float bj = in_b[colg];
        if (c == 0) {
            const int hh = colg >> 4, d = colg & 15;
#pragma unroll
            for (int r = 0; r < 16; r += 2) {
                const int rowl = (r & 3) + 8 * (r >> 2) + 4 * hi;
                const int grow = rt * 32 + rowl;
                const uint u = f2bf2((acc[r] + bj) * SC, (acc[r + 1] + bj) * SC);
                qh[((size_t)hh * npk + grow) * 16 + d] = (ushort)u;
                qh[((size_t)hh * npk + grow + 1) * 16 + d] = (ushort)(u >> 16);
            }
        } else if (c == 1) {
            const int cg2 = colg - E;
            const int hh = cg2 >> 4, d = cg2 & 15;
#pragma unroll
            for (int r = 0; r < 16; r += 2) {
                const int rowl = (r & 3) + 8 * (r >> 2) + 4 * hi;
                const int grow = rt * 32 + rowl;
                const uint u = f2bf2(acc[r] + bj, acc[r + 1] + bj);
                kh[((size_t)hh * npk + grow) * 16 + d] = (ushort)u;
                kh[((size_t)hh * npk + grow + 1) * 16 + d] = (ushort)(u >> 16);
            }
        } else {
#pragma unroll
            for (int r = 0; r < 16; ++r) {
                const int rowl = (r & 3) + 8 * (r >> 2) + 4 * hi;
                lv[w][l31][rowl] = f2bf(acc[r] + bj);
            }
            const int d = lane >> 1, half = lane & 1;
            const int dg = (ct - 8) * 32 + d;
            const int hh = dg >> 4, dl = dg & 15;
            const int sl = 2 * halfT + half;     // 16-key slice within the 64-key tile
            const short8 v0 = *(const short8*)(&lv[w][d][16 * half]);
            const short8 v1 = *(const short8*)(&lv[w][d][16 * half + 8]);
            ushort* dst = vt2 + (((size_t)(hh * NT + gt) * 4 + sl) * 16 + dl) * 16;
            *(short8*)dst = v0;
            *(short8*)(dst + 8) = v1;
        }
    }
}

// ---------------- flash attention: dense 512B V slices, VALU l-sum, 4-way split-K ----------------
__global__ __launch_bounds__(256) void k_attn18(const ushort* __restrict__ qh, const ushort* __restrict__ kh,
        const ushort* __restrict__ vt2, const int* __restrict__ starts, ushort* __restrict__ ctxb,
        int n, int npk) {
    __shared__ float po[4][32][17];
    const int NT = n >> 6;
    const int bid = blockIdx.x;
    const int h = bid & 7;          // XCD-pinned head
    const int bx = bid >> 3;
    const int tid = threadIdx.x, lane = tid & 63, w = tid >> 6;  // w 0..3
    int b = -1, bt = 0, s = 0, e = 0, cum = 0;
    for (int bb = 0; bb < NBATCH; ++bb) {
        int sb = starts[bb], eb = starts[bb + 1];
        int t = (eb - (sb & ~31) + 31) >> 5;
        if (b < 0 && bx < cum + t) { b = bb; bt = bx - cum; s = sb; e = eb; }
        cum += t;
    }
    if (b < 0) return;
    const int q0 = (s & ~31) + bt * 32;
    const int l31 = lane & 31, hi = lane >> 5;
    const short8 qf = *(const short8*)(qh + ((size_t)h * npk + q0 + l31) * 16 + 8 * hi);
    const int ks64 = s & ~63;
    const int ntk = (e - ks64 + 63) >> 6;
    const int tw = (ntk + 3) >> 2;
    const int t0 = w * tw, t1 = min(ntk, t0 + tw);

    f32x16 o, z;
#pragma unroll
    for (int i = 0; i < 16; ++i) { o[i] = 0.f; z[i] = 0.f; }
    float l_run = 0.f;

    const ushort* kbase = kh + ((size_t)h * npk + ks64 + l31) * 16 + 8 * hi;
    const ushort* vbase = vt2 + (size_t)(h * NT + (ks64 >> 6)) * 1024 + (l31 & 15) * 16 + 8 * hi;

    for (int tt = t0; tt < t1; ++tt) {
        const ushort* kp = kbase + (size_t)tt * 1024;
        const short8 ck0 = *(const short8*)kp;
        const short8 ck1 = *(const short8*)(kp + 512);
        const ushort* vt = vbase + (size_t)tt * 1024;
        const short8 vf0 = *(const short8*)(vt);          // slice 0: keys 0..15
        const short8 vf1 = *(const short8*)(vt + 256);    // slice 1: keys 16..31
        const short8 vf2 = *(const short8*)(vt + 512);    // slice 2: keys 32..47
        const short8 vf3 = *(const short8*)(vt + 768);    // slice 3: keys 48..63
        f32x16 sf0 = __builtin_amdgcn_mfma_f32_32x32x16_bf16(ck0, qf, z, 0, 0, 0);
        f32x16 sf1 = __builtin_amdgcn_mfma_f32_32x32x16_bf16(ck1, qf, z, 0, 0, 0);
        if (tt == 0 || tt == ntk - 1) {
            const int ktg = ks64 + 64 * tt;
#pragma unroll
            for (int r = 0; r < 16; ++r) {
                const int key = ktg + (r & 3) + 8 * (r >> 2) + 4 * hi;
                if (key < s || key >= e) sf0[r] = -1e30f;
                if (key + 32 < s || key + 32 >= e) sf1[r] = -1e30f;
            }
        }
        float ls = 0.f;
#pragma unroll
        for (int r = 0; r < 16; ++r) { sf0[r] = __builtin_amdgcn_exp2f(sf0[r]); ls += sf0[r]; }
        {
            uint pA0 = f2bf2(sf0[0], sf0[1]),  pA1 = f2bf2(sf0[2], sf0[3]);
            uint pA2 = f2bf2(sf0[4], sf0[5]),  pA3 = f2bf2(sf0[6], sf0[7]);
            uint pA4 = f2bf2(sf0[8], sf0[9]),  pA5 = f2bf2(sf0[10], sf0[11]);
            uint pA6 = f2bf2(sf0[12], sf0[13]), pA7 = f2bf2(sf0[14], sf0[15]);
            plswap(pA0, pA2); plswap(pA1, pA3);
            plswap(pA4, pA6); plswap(pA5, pA7);
            __builtin_amdgcn_s_setprio(1);
            o = __builtin_amdgcn_mfma_f32_32x32x16_bf16(vf0, mk8(pA0, pA1, pA2, pA3), o, 0, 0, 0);
            o = __builtin_amdgcn_mfma_f32_32x32x16_bf16(vf1, mk8(pA4, pA5, pA6, pA7), o, 0, 0, 0);
            __builtin_amdgcn_s_setprio(0);
        }
#pragma unroll
        for (int r = 0; r < 16; ++r) { sf1[r] = __builtin_amdgcn_exp2f(sf1[r]); ls += sf1[r]; }
        {
            uint pB0 = f2bf2(sf1[0], sf1[1]),  pB1 = f2bf2(sf1[2], sf1[3]);
            uint pB2 = f2bf2(sf1[4], sf1[5]),  pB3 = f2bf2(sf1[6], sf1[7]);
            uint pB4 = f2bf2(sf1[8], sf1[9]),  pB5 = f2bf2(sf1[10], sf1[11]);
            uint pB6 = f2bf2(sf1[12], sf1[13]), pB7 = f2bf2(sf1[14], sf1[15]);
            plswap(pB0, pB2); plswap(pB1, pB3);
            plswap(pB4, pB6); plswap(pB5, pB7);
            __builtin_amdgcn_s_setprio(1);
            o = __builtin_amdgcn_mfma_f32_32x32x16_bf16(vf2, mk8(pB0, pB1, pB2, pB3), o, 0, 0, 0);
            o = __builtin_amdgcn_mfma_f32_32x32x16_bf16(vf3, mk8(pB4, pB5, pB6, pB7), o, 0, 0, 0);
            __builtin_amdgcn_s_setprio(0);
        }
        l_run += ls;
    }
    l_run += __shfl_xor(l_run, 32);
#pragma unroll
    for (int r = 0; r < 8; ++r) {
        const int d = (r & 3) + 8 * (r >> 2) + 4 * hi;
        po[w][l31][d] = o[r];
    }
    if (hi == 0) po[w][l31][16] = l_run;
    __syncthreads();
    const int q = tid & 31, d0 = (tid >> 5) * 2;
    const int rowq = q0 + q;
    if (rowq >= s && rowq < e) {
        float L = 0.f, a0 = 0.f, a1 = 0.f;
#pragma unroll
        for (int ww = 0; ww < 4; ++ww) {
            L += po[ww][q][16];
            a0 += po[ww][q][d0];
            a1 += po[ww][q][d0 + 1];
        }
        const float inv = 1.f / L;
        *(uint*)(ctxb + (size_t)rowq * E + h * HD + d0) = f2bf2(a0 * inv, a1 * inv);
    }
}

// ---------------- fused epilogue: oproj+res+LN1+FFN1+GELU+FFN2+res+LN2 -> out ----------------
__global__ __launch_bounds__(256) void k_post(const ushort* __restrict__ ctxb, const ushort* __restrict__ wf2,
        const float* __restrict__ ob, const float* __restrict__ x,
        const float* __restrict__ g1, const float* __restrict__ be1,
        const ushort* __restrict__ wf3, const float* __restrict__ b1,
        const ushort* __restrict__ wf4, const float* __restrict__ b2,
        const float* __restrict__ g2, const float* __restrict__ be2,
        float* __restrict__ out, int n) {
    __shared__ float ly[32][132];
    __shared__ ushort sxb[32][136];
    __shared__ ushort hbt[32][264];
    const int rt = blockIdx.x;
    const int tid = threadIdx.x, w = tid >> 6, lane = tid & 63;
    const int l31 = lane & 31, hi = lane >> 5;
    const int row = rt * 32 + l31;
    {
        f32x16 acc;
#pragma unroll
        for (int i = 0; i < 16; ++i) acc[i] = 0.f;
#pragma unroll
        for (int kt = 0; kt < 8; ++kt) {
            const short8 af = *(const short8*)(ctxb + (size_t)row * E + kt * 16 + 8 * hi);
            const short8 bf = *(const short8*)(wf2 + ((size_t)(kt * 4 + w) * 64 + lane) * 8);
            acc = __builtin_amdgcn_mfma_f32_32x32x16_bf16(af, bf, acc, 0, 0, 0);
        }
        const int col = w * 32 + l31;
        const float bj = ob[col];
#pragma unroll
        for (int r = 0; r < 16; ++r) {
            const int rowl = (r & 3) + 8 * (r >> 2) + 4 * hi;
            ly[rowl][col] = acc[r] + bj + x[(size_t)(rt * 32 + rowl) * E + col];
        }
    }
    __syncthreads();
    {
        const int r = tid >> 3, j = tid & 7;
        float* lrow = ly[r];
        float v[16];
#pragma unroll
        for (int q = 0; q < 4; ++q) {
            const float4 t = *(const float4*)(lrow + 16 * j + 4 * q);
            v[4 * q] = t.x; v[4 * q + 1] = t.y; v[4 * q + 2] = t.z; v[4 * q + 3] = t.w;
        }
        float s = 0.f, ss = 0.f;
#pragma unroll
        for (int i = 0; i < 16; ++i) { s += v[i]; ss += v[i] * v[i]; }
        for (int m = 1; m < 8; m <<= 1) { s += __shfl_xor(s, m); ss += __shfl_xor(ss, m); }
        const float mean = s * (1.f / 128.f);
        const float var = ss * (1.f / 128.f) - mean * mean;
        const float rstd = rsqrtf(var + 1e-5f);
        float zv[16];
#pragma unroll
        for (int q = 0; q < 4; ++q) {
            const float4 gg = *(const float4*)(g1 + 16 * j + 4 * q);
            const float4 bb = *(const float4*)(be1 + 16 * j + 4 * q);
            zv[4 * q]     = (v[4 * q] - mean) * rstd * gg.x + bb.x;
            zv[4 * q + 1] = (v[4 * q + 1] - mean) * rstd * gg.y + bb.y;
            zv[4 * q + 2] = (v[4 * q + 2] - mean) * rstd * gg.z + bb.z;
            zv[4 * q + 3] = (v[4 * q + 3] - mean) * rstd * gg.w + bb.w;
            *(float4*)(lrow + 16 * j + 4 * q) = make_float4(zv[4 * q], zv[4 * q + 1], zv[4 * q + 2], zv[4 * q + 3]);
        }
        *(uint4*)(&sxb[r][16 * j]) =
            make_uint4(f2bf2(zv[0], zv[1]), f2bf2(zv[2], zv[3]), f2bf2(zv[4], zv[5]), f2bf2(zv[6], zv[7]));
        *(uint4*)(&sxb[r][16 * j + 8]) =
            make_uint4(f2bf2(zv[8], zv[9]), f2bf2(zv[10], zv[11]), f2bf2(zv[12], zv[13]), f2bf2(zv[14], zv[15]));
    }
    __syncthreads();
#pragma unroll
    for (int c = 0; c < 2; ++c) {
        const int ct = w + 4 * c;
        f32x16 acc;
#pragma unroll
        for (int i = 0; i < 16; ++i) acc[i] = 0.f;
#pragma unroll
        for (int kt = 0; kt < 8; ++kt) {
            const short8 af = *(const short8*)(&sxb[l31][kt * 16 + 8 * hi]);
            const short8 bf = *(const short8*)(wf3 + ((size_t)(kt * 8 + ct) * 64 + lane) * 8);
            acc = __builtin_amdgcn_mfma_f32_32x32x16_bf16(af, bf, acc, 0, 0, 0);
        }
        const int col = ct * 32 + l31;
        const float bj = b1[col];
#pragma unroll
        for (int r = 0; r < 16; ++r) {
            const int rowl = (r & 3) + 8 * (r >> 2) + 4 * hi;
            const float vv = acc[r] + bj;
            hbt[rowl][col] = f2bf(0.5f * vv * (1.f + erff(vv * 0.7071067811865475f)));
        }
    }
    __syncthreads();
    float res[16];
    {
        f32x16 acc;
#pragma unroll
        for (int i = 0; i < 16; ++i) acc[i] = 0.f;
#pragma unroll
        for (int kt = 0; kt < 16; ++kt) {
            const short8 af = *(const short8*)(&hbt[l31][kt * 16 + 8 * hi]);
            const short8 bf = *(const short8*)(wf4 + ((size_t)(kt * 4 + w) * 64 + lane) * 8);
            acc = __builtin_amdgcn_mfma_f32_32x32x16_bf16(af, bf, acc, 0, 0, 0);
        }
        const int col = w * 32 + l31;
        const float bj = b2[col];
#pragma unroll
        for (int r = 0; r < 16; ++r) {
            const int rowl = (r & 3) + 8 * (r >> 2) + 4 * hi;
            res[r] = acc[r] + bj + ly[rowl][col];
        }
    }
    __syncthreads();
    {
        const int col = w * 32 + l31;
#pragma unroll
        for (int r = 0; r < 16; ++r) {
            const int rowl = (r & 3) + 8 * (r >> 2) + 4 * hi;
            ly[rowl][col] = res[r];
        }
    }
    __syncthreads();
    {
        const int r = tid >> 3, j = tid & 7;
        const float* lrow = ly[r];
        float v[16];
#pragma unroll
        for (int q = 0; q < 4; ++q) {
            const float4 t = *(const float4*)(lrow + 16 * j + 4 * q);
            v[4 * q] = t.x; v[4 * q + 1] = t.y; v[4 * q + 2] = t.z; v[4 * q + 3] = t.w;
        }
        float s = 0.f, ss = 0.f;
#pragma unroll
        for (int i = 0; i < 16; ++i) { s += v[i]; ss += v[i] * v[i]; }
        for (int m = 1; m < 8; m <<= 1) { s += __shfl_xor(s, m); ss += __shfl_xor(ss, m); }
        const float mean = s * (1.f / 128.f);
        const float var = ss * (1.f / 128.f) - mean * mean;
        const float rstd = rsqrtf(var + 1e-5f);
        const int grow = rt * 32 + r;
#pragma unroll
        for (int q = 0; q < 4; ++q) {
            const float4 gg = *(const float4*)(g2 + 16 * j + 4 * q);
            const float4 bb = *(const float4*)(be2 + 16 * j + 4 * q);
            float4 o;
            o.x = (v[4 * q] - mean) * rstd * gg.x + bb.x;
            o.y = (v[4 * q + 1] - mean) * rstd * gg.y + bb.y;
            o.z = (v[4 * q + 2] - mean) * rstd * gg.z + bb.z;
            o.w = (v[4 * q + 3] - mean) * rstd * gg.w + bb.w;
            *(float4*)(out + (size_t)grow * E + 16 * j + 4 * q) = o;
        }
    }
}

extern "C" void kernel_launch(void* const* d_in, const int* in_sizes, int n_in,
                              void* d_out, int out_size, void* d_ws, size_t ws_size,
                              hipStream_t stream) {
    const float* feat   = (const float*)d_in[0];
    const int*   coords = (const int*)d_in[1];
    const float* pre_w  = (const float*)d_in[4];
    const float* pre_b  = (const float*)d_in[5];
    const float* in_w   = (const float*)d_in[6];
    const float* in_b   = (const float*)d_in[7];
    const float* out_w  = (const float*)d_in[8];
    const float* out_b  = (const float*)d_in[9];
    const float* ln1_g  = (const float*)d_in[10];
    const float* ln1_b  = (const float*)d_in[11];
    const float* w1     = (const float*)d_in[12];
    const float* b1     = (const float*)d_in[13];
    const float* w2     = (const float*)d_in[14];
    const float* b2     = (const float*)d_in[15];
    const float* ln2_g  = (const float*)d_in[16];
    const float* ln2_b  = (const float*)d_in[17];
    float* out = (float*)d_out;

    const int n = in_sizes[0] / CIN;  // 8192
    const int RT = n / 32;            // 256
    const int npk = n + 64;           // padded Q/K row count
    const int NT = n / 64;            // V tiles

    char* wsb = (char*)d_ws;
    int* starts = (int*)wsb;
    float* x    = (float*)(wsb + 256);
    ushort* qh  = (ushort*)(x + (size_t)n * E);       // [NH][npk][16]
    ushort* kh  = qh + (size_t)NH * npk * 16;         // [NH][npk][16]
    ushort* vt2 = kh + (size_t)NH * npk * 16;         // [NH][NT][4][16][16]
    ushort* ctxb = vt2 + (size_t)NH * NT * 1024;
    ushort* wf0 = ctxb + (size_t)n * E;
    ushort* wf1 = wf0 + 4 * 4 * 64 * 8;
    ushort* wf2 = wf1 + 8 * 12 * 64 * 8;
    ushort* wf3 = wf2 + 8 * 4 * 64 * 8;
    ushort* wf4 = wf3 + 8 * 8 * 64 * 8;

    k_wprep<<<dim3(32, 6), dim3(256), 0, stream>>>(pre_w, in_w, out_w, w1, w2,
                                                   wf0, wf1, wf2, wf3, wf4, coords, n, starts);
    k_preqkv<<<dim3(RT), dim3(256), 0, stream>>>(feat, wf0, pre_b, wf1, in_b, x, qh, kh, vt2, n, npk);
    k_attn18<<<dim3((n / 32 + NBATCH) * NH), dim3(256), 0, stream>>>(qh, kh, vt2, starts, ctxb, n, npk);
    k_post<<<dim3(RT), dim3(256), 0, stream>>>(ctxb, wf2, out_b, x, ln1_g, ln1_b,
                                               wf3, b1, wf4, b2, ln2_g, ln2_b, out, n);
}

// Round 19
// 64.490 us; speedup vs baseline: 1.0373x; 1.0373x over previous
//
#include <hip/hip_runtime.h>
#include <hip/hip_bf16.h>
#include <math.h>

#define CIN 64
#define E   128
#define H3  384
#define FF  256
#define NH  8
#define HD  16
#define NBATCH 4

typedef __attribute__((ext_vector_type(8))) short short8;
typedef __attribute__((ext_vector_type(16))) float f32x16;
typedef __attribute__((ext_vector_type(4))) uint uint4v;

static __device__ __forceinline__ ushort f2bf(float f) {
    uint u = __float_as_uint(f);
    return (ushort)((u + 0x7fffu + ((u >> 16) & 1u)) >> 16);
}
// packed RNE f32x2 -> bf16x2
static __device__ __forceinline__ uint f2bf2(float lo, float hi) {
    uint r;
    asm("v_cvt_pk_bf16_f32 %0, %1, %2" : "=v"(r) : "v"(lo), "v"(hi));
    return r;
}
// row swap between two VGPRs
static __device__ __forceinline__ void plswap(uint& a, uint& b) {
    auto r = __builtin_amdgcn_permlane32_swap(a, b, false, false);
    a = r[0]; b = r[1];
}
// 4 uints -> short8 fragment (SROA-proof)
static __device__ __forceinline__ short8 mk8(uint a, uint b, uint c, uint d) {
    uint4v v; v[0] = a; v[1] = b; v[2] = c; v[3] = d;
    return __builtin_bit_cast(short8, v);
}

// ---------------- weights -> bf16 MFMA B-fragment layout (+ batch bounds, m==5) ----------------
__global__ __launch_bounds__(256) void k_wprep(const float* w0, const float* w1, const float* w2,
                                               const float* w3, const float* w4,
                                               ushort* f0, ushort* f1, ushort* f2,
                                               ushort* f3, ushort* f4,
                                               const int* __restrict__ coords, int n,
                                               int* __restrict__ starts) {
    const int m = blockIdx.y;
    const int t = blockIdx.x * 256 + threadIdx.x;
    if (m == 5) {
        if (t >= n) return;
        int cur = coords[t * 4];
        int prev = (t == 0) ? -1 : coords[(t - 1) * 4];
        for (int bb = prev + 1; bb <= cur; ++bb) starts[bb] = t;
        if (t == n - 1)
            for (int bb = cur + 1; bb <= NBATCH; ++bb) starts[bb] = n;
        return;
    }
    const int Ks[5] = {CIN, E, E, E, FF};
    const int Ms[5] = {E, H3, E, FF, E};
    const float* src = m == 0 ? w0 : m == 1 ? w1 : m == 2 ? w2 : m == 3 ? w3 : w4;
    ushort* dst = m == 0 ? f0 : m == 1 ? f1 : m == 2 ? f2 : m == 3 ? f3 : f4;
    const int K = Ks[m], M = Ms[m];
    const int CT = M / 32;
    const int total = (K / 16) * CT * 64;
    if (t >= total) return;
    const int lane = t & 63;
    const int ct = (t >> 6) % CT;
    const int kt = (t >> 6) / CT;
    const int col = ct * 32 + (lane & 31);
    const int k0 = kt * 16 + 8 * (lane >> 5);
    const float* sp = src + (size_t)k0 * M + col;
    uint a = f2bf2(sp[0], sp[(size_t)M]);
    uint b = f2bf2(sp[2 * (size_t)M], sp[3 * (size_t)M]);
    uint c = f2bf2(sp[4 * (size_t)M], sp[5 * (size_t)M]);
    uint d = f2bf2(sp[6 * (size_t)M], sp[7 * (size_t)M]);
    *(short8*)(dst + (size_t)t * 8) = mk8(a, b, c, d);
}

// ---------------- fused: x = feat@pre_w+pre_b ; qkv = x@in_w+in_b ----------------
// vt2 layout: [h][tile64][slice 0..3][32 dims][16 keys]  (dims 16..31 = 1.0 for l-trick)
__global__ __launch_bounds__(256) void k_preqkv(const float* __restrict__ feat, const ushort* __restrict__ wf0,
        const float* __restrict__ pre_b, const ushort* __restrict__ wf1, const float* __restrict__ in_b,
        float* __restrict__ x, ushort* __restrict__ qh, ushort* __restrict__ kh, ushort* __restrict__ vt2,
        int n, int npk) {
    __shared__ ushort sxb[32][136];
    __shared__ ushort lv[4][32][34];
    const int rt = blockIdx.x;
    const int NT = n >> 6;
    const int tid = threadIdx.x, w = tid >> 6, lane = tid & 63;
    const int l31 = lane & 31, hi = lane >> 5;
    const int row = rt * 32 + l31;
    const int gt = rt >> 1, halfT = rt & 1;   // 64-key tile, which 32-key half
    const float SC = 0.25f * 1.4426950408889634f;
    {   // ones rows (dims 16..31) for this rt's two slices
        const uint ONE2 = 0x3F803F80u;
        for (int it = tid; it < 512; it += 256) {
            const int hh = it >> 6, rem = it & 63;
            const int sl = 2 * halfT + (rem >> 5);
            const int rloc = (rem >> 1) & 15, seg = rem & 1;
            *(uint4*)(vt2 + (((size_t)(hh * NT + gt) * 4 + sl) * 32 + 16 + rloc) * 16 + seg * 8) =
                make_uint4(ONE2, ONE2, ONE2, ONE2);
        }
    }
    {
        f32x16 acc;
#pragma unroll
        for (int i = 0; i < 16; ++i) acc[i] = 0.f;
#pragma unroll
        for (int kt = 0; kt < 4; ++kt) {
            const float* ap = feat + (size_t)row * CIN + kt * 16 + 8 * hi;
            const float4 a0 = *(const float4*)ap;
            const float4 a1 = *(const float4*)(ap + 4);
            const short8 af = mk8(f2bf2(a0.x, a0.y), f2bf2(a0.z, a0.w),
                                  f2bf2(a1.x, a1.y), f2bf2(a1.z, a1.w));
            const short8 bf = *(const short8*)(wf0 + ((size_t)(kt * 4 + w) * 64 + lane) * 8);
            acc = __builtin_amdgcn_mfma_f32_32x32x16_bf16(af, bf, acc, 0, 0, 0);
        }
        const int col = w * 32 + l31;
        const float bj = pre_b[col];
#pragma unroll
        for (int r = 0; r < 16; ++r) {
            const int rowl = (r & 3) + 8 * (r >> 2) + 4 * hi;
            const float v = acc[r] + bj;
            x[(size_t)(rt * 32 + rowl) * E + col] = v;
            sxb[rowl][col] = f2bf(v);
        }
    }
    __syncthreads();
#pragma unroll
    for (int c = 0; c < 3; ++c) {
        const int ct = w + 4 * c;
        f32x16 acc;
#pragma unroll
        for (int i = 0; i < 16; ++i) acc[i] = 0.f;
#pragma unroll
        for (int kt = 0; kt < 8; ++kt) {
            const short8 af = *(const short8*)(&sxb[l31][kt * 16 + 8 * hi]);
            const short8 bf = *(const short8*)(wf1 + ((size_t)(kt * 12 + ct) * 64 + lane) * 8);
            acc = __builtin_amdgcn_mfma_f32_32x32x16_bf16(af, bf, acc, 0, 0, 0);
        }
        const int colg = ct * 32 + l31;
        const float bj = in_b[colg];
        if (c == 0) {
            const int hh = colg >> 4, d = colg & 15;
#pragma unroll
            for (int r = 0; r < 16; r += 2) {
                const int rowl = (r & 3) + 8 * (r >> 2) + 4 * hi;
                const int grow = rt * 32 + rowl;
                const uint u = f2bf2((acc[r] + bj) * SC, (acc[r + 1] + bj) * SC);
                qh[((size_t)hh * npk + grow) * 16 + d] = (ushort)u;
                qh[((size_t)hh * npk + grow + 1) * 16 + d] = (ushort)(u >> 16);
            }
        } else if (c == 1) {
            const int cg2 = colg - E;
            const int hh = cg2 >> 4, d = cg2 & 15;
#pragma unroll
            for (int r = 0; r < 16; r += 2) {
                const int rowl = (r & 3) + 8 * (r >> 2) + 4 * hi;
                const int grow = rt * 32 + rowl;
                const uint u = f2bf2(acc[r] + bj, acc[r + 1] + bj);
                kh[((size_t)hh * npk + grow) * 16 + d] = (ushort)u;
                kh[((size_t)hh * npk + grow + 1) * 16 + d] = (ushort)(u >> 16);
            }
        } else {
#pragma unroll
            for (int r = 0; r < 16; ++r) {
                const int rowl = (r & 3) + 8 * (r >> 2) + 4 * hi;
                lv[w][l31][rowl] = f2bf(acc[r] + bj);
            }
            const int d = lane >> 1, half = lane & 1;
            const int dg = (ct - 8) * 32 + d;
            const int hh = dg >> 4, dl = dg & 15;
            const int sl = 2 * halfT + half;     // 16-key slice within the 64-key tile
            const short8 v0 = *(const short8*)(&lv[w][d][16 * half]);
            const short8 v1 = *(const short8*)(&lv[w][d][16 * half + 8]);
            ushort* dst = vt2 + (((size_t)(hh * NT + gt) * 4 + sl) * 32 + dl) * 16;
            *(short8*)dst = v0;
            *(short8*)(dst + 8) = v1;
        }
    }
}

// ---------------- flash attention: slice-major V (min cache lines), 4-way split-K ----------------
__global__ __launch_bounds__(256) void k_attn17(const ushort* __restrict__ qh, const ushort* __restrict__ kh,
        const ushort* __restrict__ vt2, const int* __restrict__ starts, ushort* __restrict__ ctxb,
        int n, int npk) {
    __shared__ float po[4][32][17];
    const int NT = n >> 6;
    const int bid = blockIdx.x;
    const int h = bid & 7;          // XCD-pinned head
    const int bx = bid >> 3;
    const int tid = threadIdx.x, lane = tid & 63, w = tid >> 6;  // w 0..3
    int b = -1, bt = 0, s = 0, e = 0, cum = 0;
    for (int bb = 0; bb < NBATCH; ++bb) {
        int sb = starts[bb], eb = starts[bb + 1];
        int t = (eb - (sb & ~31) + 31) >> 5;
        if (b < 0 && bx < cum + t) { b = bb; bt = bx - cum; s = sb; e = eb; }
        cum += t;
    }
    if (b < 0) return;
    const int q0 = (s & ~31) + bt * 32;
    const int l31 = lane & 31, hi = lane >> 5;
    const short8 qf = *(const short8*)(qh + ((size_t)h * npk + q0 + l31) * 16 + 8 * hi);
    const int ks64 = s & ~63;
    const int ntk = (e - ks64 + 63) >> 6;
    const int tw = (ntk + 3) >> 2;
    const int t0 = w * tw, t1 = min(ntk, t0 + tw);

    f32x16 o, z;
#pragma unroll
    for (int i = 0; i < 16; ++i) { o[i] = 0.f; z[i] = 0.f; }

    const ushort* kbase = kh + ((size_t)h * npk + ks64 + l31) * 16 + 8 * hi;
    const ushort* vbase = vt2 + (size_t)(h * NT + (ks64 >> 6)) * 2048 + l31 * 16 + 8 * hi;

    for (int tt = t0; tt < t1; ++tt) {
        const ushort* kp = kbase + (size_t)tt * 1024;
        const short8 ck0 = *(const short8*)kp;
        const short8 ck1 = *(const short8*)(kp + 512);
        const ushort* vt = vbase + (size_t)tt * 2048;
        const short8 vf0 = *(const short8*)(vt);          // slice 0: keys 0..15
        const short8 vf1 = *(const short8*)(vt + 512);    // slice 1: keys 16..31
        const short8 vf2 = *(const short8*)(vt + 1024);   // slice 2: keys 32..47
        const short8 vf3 = *(const short8*)(vt + 1536);   // slice 3: keys 48..63
        f32x16 sf0 = __builtin_amdgcn_mfma_f32_32x32x16_bf16(ck0, qf, z, 0, 0, 0);
        f32x16 sf1 = __builtin_amdgcn_mfma_f32_32x32x16_bf16(ck1, qf, z, 0, 0, 0);
        if (tt == 0 || tt == ntk - 1) {
            const int ktg = ks64 + 64 * tt;
#pragma unroll
            for (int r = 0; r < 16; ++r) {
                const int key = ktg + (r & 3) + 8 * (r >> 2) + 4 * hi;
                if (key < s || key >= e) sf0[r] = -1e30f;
                if (key + 32 < s || key + 32 >= e) sf1[r] = -1e30f;
            }
        }
#pragma unroll
        for (int r = 0; r < 16; ++r) sf0[r] = __builtin_amdgcn_exp2f(sf0[r]);
        {
            uint pA0 = f2bf2(sf0[0], sf0[1]),  pA1 = f2bf2(sf0[2], sf0[3]);
            uint pA2 = f2bf2(sf0[4], sf0[5]),  pA3 = f2bf2(sf0[6], sf0[7]);
            uint pA4 = f2bf2(sf0[8], sf0[9]),  pA5 = f2bf2(sf0[10], sf0[11]);
            uint pA6 = f2bf2(sf0[12], sf0[13]), pA7 = f2bf2(sf0[14], sf0[15]);
            plswap(pA0, pA2); plswap(pA1, pA3);
            plswap(pA4, pA6); plswap(pA5, pA7);
            __builtin_amdgcn_s_setprio(1);
            o = __builtin_amdgcn_mfma_f32_32x32x16_bf16(vf0, mk8(pA0, pA1, pA2, pA3), o, 0, 0, 0);
            o = __builtin_amdgcn_mfma_f32_32x32x16_bf16(vf1, mk8(pA4, pA5, pA6, pA7), o, 0, 0, 0);
            __builtin_amdgcn_s_setprio(0);
        }
#pragma unroll
        for (int r = 0; r < 16; ++r) sf1[r] = __builtin_amdgcn_exp2f(sf1[r]);
        {
            uint pB0 = f2bf2(sf1[0], sf1[1]),  pB1 = f2bf2(sf1[2], sf1[3]);
            uint pB2 = f2bf2(sf1[4], sf1[5]),  pB3 = f2bf2(sf1[6], sf1[7]);
            uint pB4 = f2bf2(sf1[8], sf1[9]),  pB5 = f2bf2(sf1[10], sf1[11]);
            uint pB6 = f2bf2(sf1[12], sf1[13]), pB7 = f2bf2(sf1[14], sf1[15]);
            plswap(pB0, pB2); plswap(pB1, pB3);
            plswap(pB4, pB6); plswap(pB5, pB7);
            __builtin_amdgcn_s_setprio(1);
            o = __builtin_amdgcn_mfma_f32_32x32x16_bf16(vf2, mk8(pB0, pB1, pB2, pB3), o, 0, 0, 0);
            o = __builtin_amdgcn_mfma_f32_32x32x16_bf16(vf3, mk8(pB4, pB5, pB6, pB7), o, 0, 0, 0);
            __builtin_amdgcn_s_setprio(0);
        }
    }
#pragma unroll
    for (int r = 0; r < 8; ++r) {
        const int d = (r & 3) + 8 * (r >> 2) + 4 * hi;
        po[w][l31][d] = o[r];
    }
    if (hi == 0) po[w][l31][16] = o[8];
    __syncthreads();
    const int q = tid & 31, d0 = (tid >> 5) * 2;
    const int rowq = q0 + q;
    if (rowq >= s && rowq < e) {
        float L = 0.f, a0 = 0.f, a1 = 0.f;
#pragma unroll
        for (int ww = 0; ww < 4; ++ww) {
            L += po[ww][q][16];
            a0 += po[ww][q][d0];
            a1 += po[ww][q][d0 + 1];
        }
        const float inv = 1.f / L;
        *(uint*)(ctxb + (size_t)rowq * E + h * HD + d0) = f2bf2(a0 * inv, a1 * inv);
    }
}

// ---------------- fused epilogue: oproj+res+LN1+FFN1+GELU+FFN2+res+LN2 -> out ----------------
__global__ __launch_bounds__(256) void k_post(const ushort* __restrict__ ctxb, const ushort* __restrict__ wf2,
        const float* __restrict__ ob, const float* __restrict__ x,
        const float* __restrict__ g1, const float* __restrict__ be1,
        const ushort* __restrict__ wf3, const float* __restrict__ b1,
        const ushort* __restrict__ wf4, const float* __restrict__ b2,
        const float* __restrict__ g2, const float* __restrict__ be2,
        float* __restrict__ out, int n) {
    __shared__ float ly[32][132];
    __shared__ ushort sxb[32][136];
    __shared__ ushort hbt[32][264];
    const int rt = blockIdx.x;
    const int tid = threadIdx.x, w = tid >> 6, lane = tid & 63;
    const int l31 = lane & 31, hi = lane >> 5;
    const int row = rt * 32 + l31;
    {
        f32x16 acc;
#pragma unroll
        for (int i = 0; i < 16; ++i) acc[i] = 0.f;
#pragma unroll
        for (int kt = 0; kt < 8; ++kt) {
            const short8 af = *(const short8*)(ctxb + (size_t)row * E + kt * 16 + 8 * hi);
            const short8 bf = *(const short8*)(wf2 + ((size_t)(kt * 4 + w) * 64 + lane) * 8);
            acc = __builtin_amdgcn_mfma_f32_32x32x16_bf16(af, bf, acc, 0, 0, 0);
        }
        const int col = w * 32 + l31;
        const float bj = ob[col];
#pragma unroll
        for (int r = 0; r < 16; ++r) {
            const int rowl = (r & 3) + 8 * (r >> 2) + 4 * hi;
            ly[rowl][col] = acc[r] + bj + x[(size_t)(rt * 32 + rowl) * E + col];
        }
    }
    __syncthreads();
    {
        const int r = tid >> 3, j = tid & 7;
        float* lrow = ly[r];
        float v[16];
#pragma unroll
        for (int q = 0; q < 4; ++q) {
            const float4 t = *(const float4*)(lrow + 16 * j + 4 * q);
            v[4 * q] = t.x; v[4 * q + 1] = t.y; v[4 * q + 2] = t.z; v[4 * q + 3] = t.w;
        }
        float s = 0.f, ss = 0.f;
#pragma unroll
        for (int i = 0; i < 16; ++i) { s += v[i]; ss += v[i] * v[i]; }
        for (int m = 1; m < 8; m <<= 1) { s += __shfl_xor(s, m); ss += __shfl_xor(ss, m); }
        const float mean = s * (1.f / 128.f);
        const float var = ss * (1.f / 128.f) - mean * mean;
        const float rstd = rsqrtf(var + 1e-5f);
        float zv[16];
#pragma unroll
        for (int q = 0; q < 4; ++q) {
            const float4 gg = *(const float4*)(g1 + 16 * j + 4 * q);
            const float4 bb = *(const float4*)(be1 + 16 * j + 4 * q);
            zv[4 * q]     = (v[4 * q] - mean) * rstd * gg.x + bb.x;
            zv[4 * q + 1] = (v[4 * q + 1] - mean) * rstd * gg.y + bb.y;
            zv[4 * q + 2] = (v[4 * q + 2] - mean) * rstd * gg.z + bb.z;
            zv[4 * q + 3] = (v[4 * q + 3] - mean) * rstd * gg.w + bb.w;
            *(float4*)(lrow + 16 * j + 4 * q) = make_float4(zv[4 * q], zv[4 * q + 1], zv[4 * q + 2], zv[4 * q + 3]);
        }
        *(uint4*)(&sxb[r][16 * j]) =
            make_uint4(f2bf2(zv[0], zv[1]), f2bf2(zv[2], zv[3]), f2bf2(zv[4], zv[5]), f2bf2(zv[6], zv[7]));
        *(uint4*)(&sxb[r][16 * j + 8]) =
            make_uint4(f2bf2(zv[8], zv[9]), f2bf2(zv[10], zv[11]), f2bf2(zv[12], zv[13]), f2bf2(zv[14], zv[15]));
    }
    __syncthreads();
#pragma unroll
    for (int c = 0; c < 2; ++c) {
        const int ct = w + 4 * c;
        f32x16 acc;
#pragma unroll
        for (int i = 0; i < 16; ++i) acc[i] = 0.f;
#pragma unroll
        for (int kt = 0; kt < 8; ++kt) {
            const short8 af = *(const short8*)(&sxb[l31][kt * 16 + 8 * hi]);
            const short8 bf = *(const short8*)(wf3 + ((size_t)(kt * 8 + ct) * 64 + lane) * 8);
            acc = __builtin_amdgcn_mfma_f32_32x32x16_bf16(af, bf, acc, 0, 0, 0);
        }
        const int col = ct * 32 + l31;
        const float bj = b1[col];
#pragma unroll
        for (int r = 0; r < 16; ++r) {
            const int rowl = (r & 3) + 8 * (r >> 2) + 4 * hi;
            const float vv = acc[r] + bj;
            hbt[rowl][col] = f2bf(0.5f * vv * (1.f + erff(vv * 0.7071067811865475f)));
        }
    }
    __syncthreads();
    float res[16];
    {
        f32x16 acc;
#pragma unroll
        for (int i = 0; i < 16; ++i) acc[i] = 0.f;
#pragma unroll
        for (int kt = 0; kt < 16; ++kt) {
            const short8 af = *(const short8*)(&hbt[l31][kt * 16 + 8 * hi]);
            const short8 bf = *(const short8*)(wf4 + ((size_t)(kt * 4 + w) * 64 + lane) * 8);
            acc = __builtin_amdgcn_mfma_f32_32x32x16_bf16(af, bf, acc, 0, 0, 0);
        }
        const int col = w * 32 + l31;
        const float bj = b2[col];
#pragma unroll
        for (int r = 0; r < 16; ++r) {
            const int rowl = (r & 3) + 8 * (r >> 2) + 4 * hi;
            res[r] = acc[r] + bj + ly[rowl][col];
        }
    }
    __syncthreads();
    {
        const int col = w * 32 + l31;
#pragma unroll
        for (int r = 0; r < 16; ++r) {
            const int rowl = (r & 3) + 8 * (r >> 2) + 4 * hi;
            ly[rowl][col] = res[r];
        }
    }
    __syncthreads();
    {
        const int r = tid >> 3, j = tid & 7;
        const float* lrow = ly[r];
        float v[16];
#pragma unroll
        for (int q = 0; q < 4; ++q) {
            const float4 t = *(const float4*)(lrow + 16 * j + 4 * q);
            v[4 * q] = t.x; v[4 * q + 1] = t.y; v[4 * q + 2] = t.z; v[4 * q + 3] = t.w;
        }
        float s = 0.f, ss = 0.f;
#pragma unroll
        for (int i = 0; i < 16; ++i) { s += v[i]; ss += v[i] * v[i]; }
        for (int m = 1; m < 8; m <<= 1) { s += __shfl_xor(s, m); ss += __shfl_xor(ss, m); }
        const float mean = s * (1.f / 128.f);
        const float var = ss * (1.f / 128.f) - mean * mean;
        const float rstd = rsqrtf(var + 1e-5f);
        const int grow = rt * 32 + r;
#pragma unroll
        for (int q = 0; q < 4; ++q) {
            const float4 gg = *(const float4*)(g2 + 16 * j + 4 * q);
            const float4 bb = *(const float4*)(be2 + 16 * j + 4 * q);
            float4 o;
            o.x = (v[4 * q] - mean) * rstd * gg.x + bb.x;
            o.y = (v[4 * q + 1] - mean) * rstd * gg.y + bb.y;
            o.z = (v[4 * q + 2] - mean) * rstd * gg.z + bb.z;
            o.w = (v[4 * q + 3] - mean) * rstd * gg.w + bb.w;
            *(float4*)(out + (size_t)grow * E + 16 * j + 4 * q) = o;
        }
    }
}

extern "C" void kernel_launch(void* const* d_in, const int* in_sizes, int n_in,
                              void* d_out, int out_size, void* d_ws, size_t ws_size,
                              hipStream_t stream) {
    const float* feat   = (const float*)d_in[0];
    const int*   coords = (const int*)d_in[1];
    const float* pre_w  = (const float*)d_in[4];
    const float* pre_b  = (const float*)d_in[5];
    const float* in_w   = (const float*)d_in[6];
    const float* in_b   = (const float*)d_in[7];
    const float* out_w  = (const float*)d_in[8];
    const float* out_b  = (const float*)d_in[9];
    const float* ln1_g  = (const float*)d_in[10];
    const float* ln1_b  = (const float*)d_in[11];
    const float* w1     = (const float*)d_in[12];
    const float* b1     = (const float*)d_in[13];
    const float* w2     = (const float*)d_in[14];
    const float* b2     = (const float*)d_in[15];
    const float* ln2_g  = (const float*)d_in[16];
    const float* ln2_b  = (const float*)d_in[17];
    float* out = (float*)d_out;

    const int n = in_sizes[0] / CIN;  // 8192
    const int RT = n / 32;            // 256
    const int npk = n + 64;           // padded Q/K row count
    const int NT = n / 64;            // V tiles

    char* wsb = (char*)d_ws;
    int* starts = (int*)wsb;
    float* x    = (float*)(wsb + 256);
    ushort* qh  = (ushort*)(x + (size_t)n * E);       // [NH][npk][16]
    ushort* kh  = qh + (size_t)NH * npk * 16;         // [NH][npk][16]
    ushort* vt2 = kh + (size_t)NH * npk * 16;         // [NH][NT][4][32][16]
    ushort* ctxb = vt2 + (size_t)NH * NT * 2048;
    ushort* wf0 = ctxb + (size_t)n * E;
    ushort* wf1 = wf0 + 4 * 4 * 64 * 8;
    ushort* wf2 = wf1 + 8 * 12 * 64 * 8;
    ushort* wf3 = wf2 + 8 * 4 * 64 * 8;
    ushort* wf4 = wf3 + 8 * 8 * 64 * 8;

    k_wprep<<<dim3(32, 6), dim3(256), 0, stream>>>(pre_w, in_w, out_w, w1, w2,
                                                   wf0, wf1, wf2, wf3, wf4, coords, n, starts);
    k_preqkv<<<dim3(RT), dim3(256), 0, stream>>>(feat, wf0, pre_b, wf1, in_b, x, qh, kh, vt2, n, npk);
    k_attn17<<<dim3((n / 32 + NBATCH) * NH), dim3(256), 0, stream>>>(qh, kh, vt2, starts, ctxb, n, npk);
    k_post<<<dim3(RT), dim3(256), 0, stream>>>(ctxb, wf2, out_b, x, ln1_g, ln1_b,
                                               wf3, b1, wf4, b2, ln2_g, ln2_b, out, n);
}